// Round 1
// baseline (649.703 us; speedup 1.0000x reference)
//
#include <hip/hip_runtime.h>
#include <hip/hip_bf16.h>

typedef __bf16 bf16x8 __attribute__((ext_vector_type(8)));
typedef float  f32x4  __attribute__((ext_vector_type(4)));
typedef __hip_bfloat16 bf16;

#define MFMA16(a,b,c) __builtin_amdgcn_mfma_f32_16x16x32_bf16(a,b,c,0,0,0)

__device__ __forceinline__ void gload_lds16(const void* g, void* l){
  __builtin_amdgcn_global_load_lds((const __attribute__((address_space(1))) void*)g,
                                   (__attribute__((address_space(3))) void*)l, 16, 0, 0);
}

// ---------------- fp32 -> bf16 elementwise convert ----------------
__global__ __launch_bounds__(256) void k_cvt(const float* __restrict__ in,
                                             bf16* __restrict__ out, int n4){
  int stride = gridDim.x * blockDim.x;
  for (int i = blockIdx.x * blockDim.x + threadIdx.x; i < n4; i += stride){
    float4 v = ((const float4*)in)[i];
    bf16 o[4] = {__float2bfloat16(v.x), __float2bfloat16(v.y),
                 __float2bfloat16(v.z), __float2bfloat16(v.w)};
    *(ushort4*)(out + 4*(size_t)i) = *(ushort4*)o;
  }
}

// ---------------- fp32 [R][C] -> bf16 transposed [C][R] ----------------
__global__ __launch_bounds__(256) void k_tr(const float* __restrict__ in,
                                            bf16* __restrict__ out, int R, int C){
  __shared__ float t[32][33];
  int c0 = blockIdx.x*32, r0 = blockIdx.y*32;
  int x = threadIdx.x, y0 = threadIdx.y;
  for (int j = y0; j < 32; j += 8) t[j][x] = in[(size_t)(r0+j)*C + c0 + x];
  __syncthreads();
  for (int j = y0; j < 32; j += 8)
    out[(size_t)(c0+j)*R + r0 + x] = __float2bfloat16(t[x][j]);
}

// ---------------- bf16 GEMM: C[M][N] = A[M][K] @ Bt[N][K]^T + bias ----------------
// 128x128 tile, BK=32, 4 waves (2x2), each wave 64x64 = 4x4 MFMA frags.
template<bool OUTF32>
__global__ __launch_bounds__(256,2) void k_gemm(const bf16* __restrict__ A,
                                                const bf16* __restrict__ Bt,
                                                const float* __restrict__ bias,
                                                void* __restrict__ Cv,
                                                int M, int N, int K){
  __shared__ bf16 As[128*32];
  __shared__ bf16 Bs[128*32];
  const int tid = threadIdx.x, w = tid>>6, l = tid&63;
  const int wm = w>>1, wn = w&1, lg = l>>4, li = l&15;
  const int m0 = blockIdx.y*128, n0 = blockIdx.x*128;

  f32x4 acc[4][4];
  #pragma unroll
  for (int m=0;m<4;m++)
    #pragma unroll
    for (int n=0;n<4;n++) acc[m][n] = (f32x4){0.f,0.f,0.f,0.f};

  for (int k0 = 0; k0 < K; k0 += 32){
    #pragma unroll
    for (int i=0;i<2;i++){
      int u = i*256 + w*64 + l;        // 16B chunk index within the 8KB tile
      int r = u>>2, c = (u&3)*8;       // row, col(elem) in [128][32]
      gload_lds16(A  + (size_t)(m0+r)*K + k0 + c, As + (size_t)(i*256 + w*64)*8);
      gload_lds16(Bt + (size_t)(n0+r)*K + k0 + c, Bs + (size_t)(i*256 + w*64)*8);
    }
    __syncthreads();
    bf16x8 af[4], bfv[4];
    #pragma unroll
    for (int m=0;m<4;m++) af[m]  = *(const bf16x8*)(As + (size_t)(wm*64 + m*16 + li)*32 + lg*8);
    #pragma unroll
    for (int n=0;n<4;n++) bfv[n] = *(const bf16x8*)(Bs + (size_t)(wn*64 + n*16 + li)*32 + lg*8);
    #pragma unroll
    for (int m=0;m<4;m++)
      #pragma unroll
      for (int n=0;n<4;n++)
        acc[m][n] = MFMA16(af[m], bfv[n], acc[m][n]);
    __syncthreads();
  }

  #pragma unroll
  for (int m=0;m<4;m++)
    #pragma unroll
    for (int n=0;n<4;n++)
      #pragma unroll
      for (int r4=0;r4<4;r4++){
        int row = m0 + wm*64 + m*16 + lg*4 + r4;
        int col = n0 + wn*64 + n*16 + li;
        float v = acc[m][n][r4] + bias[col];
        if (OUTF32) ((float*)Cv)[(size_t)row*N + col] = v;
        else        ((bf16*)Cv)[(size_t)row*N + col] = __float2bfloat16(v);
      }
}

// ---------------- causal flash attention ----------------
// qkv: [B*S][6144] bf16 (Q cols h*128, K cols 2048+h*128, V cols 4096+h*128)
// O:   [B*S][2048] bf16 (head-merged)
// grid (qb=16, h=16, b=4), block 256 = 4 waves, wave w owns q rows w*32..w*32+31.
#define ATT_SCALE 0.08838834764831845f

__global__ __launch_bounds__(256,2) void k_attn(const bf16* __restrict__ qkv,
                                                bf16* __restrict__ O){
  const int qb = blockIdx.x, h = blockIdx.y, b = blockIdx.z;
  const int tid = threadIdx.x, w = tid>>6, l = tid&63;
  const int lg = l>>4, li = l&15;
  const size_t RS = 6144;

  __shared__ bf16 Kt[64][136];    // [key][hd]   (272B row stride: 16B-mult, 2-way banks)
  __shared__ bf16 Vt[128][72];    // [hd][key]   (144B row stride)
  __shared__ bf16 Pt[4][32][72];  // per-wave P  [qrow][key]

  // Q fragments in registers (reused across all k-tiles)
  const bf16* qptr = qkv + ((size_t)(b*2048 + qb*128 + w*32))*RS + h*128;
  bf16x8 qf[2][4];
  #pragma unroll
  for (int m=0;m<2;m++)
    #pragma unroll
    for (int ks=0;ks<4;ks++)
      qf[m][ks] = *(const bf16x8*)(qptr + (size_t)(m*16+li)*RS + ks*32 + lg*8);

  f32x4 acc[2][8];
  #pragma unroll
  for (int m=0;m<2;m++)
    #pragma unroll
    for (int n=0;n<8;n++) acc[m][n] = (f32x4){0.f,0.f,0.f,0.f};
  float mst[8], lst[8];
  #pragma unroll
  for (int i=0;i<8;i++){ mst[i] = -1e30f; lst[i] = 0.f; }

  const int nkt = 2*(qb+1);
  for (int kt = 0; kt < nkt; ++kt){
    // ---- stage K tile [64][128] (coalesced) ----
    const bf16* kbase = qkv + ((size_t)(b*2048 + kt*64))*RS + 2048 + h*128;
    #pragma unroll
    for (int i=0;i<4;i++){
      int u = i*256 + tid;
      int r = u>>4, c = (u&15)*8;
      *(bf16x8*)(&Kt[r][c]) = *(const bf16x8*)(kbase + (size_t)r*RS + c);
    }
    // ---- stage V tile transposed -> Vt[128][64] ----
    const bf16* vbase = qkv + ((size_t)(b*2048 + kt*64))*RS + 4096 + h*128;
    #pragma unroll
    for (int i=0;i<4;i++){
      int key = i*16 + (tid&15);
      int d0  = ((tid>>4)&15)*8;
      bf16x8 v = *(const bf16x8*)(vbase + (size_t)key*RS + d0);
      #pragma unroll
      for (int j=0;j<8;j++) Vt[d0+j][key] = ((const bf16*)&v)[j];
    }
    __syncthreads();

    // ---- S = Q @ K^T ----
    f32x4 s[2][4];
    #pragma unroll
    for (int m=0;m<2;m++)
      #pragma unroll
      for (int n=0;n<4;n++) s[m][n] = (f32x4){0.f,0.f,0.f,0.f};
    #pragma unroll
    for (int ks=0;ks<4;ks++){
      bf16x8 kf[4];
      #pragma unroll
      for (int n=0;n<4;n++) kf[n] = *(const bf16x8*)(&Kt[n*16+li][ks*32 + lg*8]);
      #pragma unroll
      for (int m=0;m<2;m++)
        #pragma unroll
        for (int n=0;n<4;n++) s[m][n] = MFMA16(qf[m][ks], kf[n], s[m][n]);
    }

    // ---- scale + causal mask ----
    #pragma unroll
    for (int m=0;m<2;m++)
      #pragma unroll
      for (int n=0;n<4;n++){
        int key = kt*64 + n*16 + li;
        #pragma unroll
        for (int r4=0;r4<4;r4++){
          int qrow = qb*128 + w*32 + m*16 + lg*4 + r4;
          float v = s[m][n][r4]*ATT_SCALE;
          s[m][n][r4] = (key <= qrow) ? v : -1e30f;
        }
      }

    // ---- online softmax (row lives across 16 lanes) ----
    #pragma unroll
    for (int m=0;m<2;m++)
      #pragma unroll
      for (int r4=0;r4<4;r4++){
        int idx = m*4 + r4;
        float rm = fmaxf(fmaxf(s[m][0][r4], s[m][1][r4]),
                         fmaxf(s[m][2][r4], s[m][3][r4]));
        rm = fmaxf(rm, __shfl_xor(rm, 1));
        rm = fmaxf(rm, __shfl_xor(rm, 2));
        rm = fmaxf(rm, __shfl_xor(rm, 4));
        rm = fmaxf(rm, __shfl_xor(rm, 8));
        float mnew = fmaxf(mst[idx], rm);
        float corr = __expf(mst[idx] - mnew);
        mst[idx] = mnew;
        float ps = 0.f;
        #pragma unroll
        for (int n=0;n<4;n++){
          float p = __expf(s[m][n][r4] - mnew);
          s[m][n][r4] = p; ps += p;
        }
        ps += __shfl_xor(ps, 1);
        ps += __shfl_xor(ps, 2);
        ps += __shfl_xor(ps, 4);
        ps += __shfl_xor(ps, 8);
        lst[idx] = lst[idx]*corr + ps;
        #pragma unroll
        for (int n=0;n<8;n++) acc[m][n][r4] *= corr;
      }

    // ---- P -> LDS (bf16) for PV re-layout ----
    #pragma unroll
    for (int m=0;m<2;m++)
      #pragma unroll
      for (int n=0;n<4;n++)
        #pragma unroll
        for (int r4=0;r4<4;r4++)
          Pt[w][m*16 + lg*4 + r4][n*16 + li] = __float2bfloat16(s[m][n][r4]);

    // ---- O += P @ V ----
    #pragma unroll
    for (int ks=0;ks<2;ks++){
      bf16x8 pa[2];
      #pragma unroll
      for (int m=0;m<2;m++) pa[m] = *(const bf16x8*)(&Pt[w][m*16+li][ks*32 + lg*8]);
      #pragma unroll
      for (int n=0;n<8;n++){
        bf16x8 vf = *(const bf16x8*)(&Vt[n*16+li][ks*32 + lg*8]);
        #pragma unroll
        for (int m=0;m<2;m++) acc[m][n] = MFMA16(pa[m], vf, acc[m][n]);
      }
    }
    __syncthreads();
  }

  // ---- epilogue: O = acc / l ----
  bf16* obase = O + ((size_t)(b*2048 + qb*128 + w*32))*2048 + h*128;
  #pragma unroll
  for (int m=0;m<2;m++)
    #pragma unroll
    for (int n=0;n<8;n++)
      #pragma unroll
      for (int r4=0;r4<4;r4++){
        float v = acc[m][n][r4] / lst[m*4 + r4];
        obase[(size_t)(m*16 + lg*4 + r4)*2048 + n*16 + li] = __float2bfloat16(v);
      }
}

// ---------------- launch ----------------
extern "C" void kernel_launch(void* const* d_in, const int* in_sizes, int n_in,
                              void* d_out, int out_size, void* d_ws, size_t ws_size,
                              hipStream_t stream) {
  const float* X      = (const float*)d_in[0];  // [4,2048,2048]
  const float* W_attn = (const float*)d_in[1];  // [2048,6144]
  const float* b_attn = (const float*)d_in[2];  // [6144]
  const float* W_proj = (const float*)d_in[3];  // [2048,2048]
  const float* b_proj = (const float*)d_in[4];  // [2048]
  float* out = (float*)d_out;                   // [4,2048,2048] fp32

  char* ws = (char*)d_ws;
  bf16* Xb  = (bf16*)(ws);                        // 8192*2048*2  = 33,554,432 B
  bf16* Wat = (bf16*)(ws + 33554432);             // 6144*2048*2  = 25,165,824 B
  bf16* Wpt = (bf16*)(ws + 58720256);             // 2048*2048*2  =  8,388,608 B
  bf16* QKV = (bf16*)(ws + 67108864);             // 8192*6144*2  = 100,663,296 B
  bf16* Obf = Xb;  // alias: Xb dead after GEMM1  // total 167,772,160 B

  // converts
  k_cvt<<<2048, 256, 0, stream>>>(X, Xb, 8192*2048/4);
  k_tr <<<dim3(192,64), dim3(32,8), 0, stream>>>(W_attn, Wat, 2048, 6144);
  k_tr <<<dim3(64,64),  dim3(32,8), 0, stream>>>(W_proj, Wpt, 2048, 2048);

  // QKV = Xb @ W_attn + b_attn   (bf16 out)
  k_gemm<false><<<dim3(48,64), 256, 0, stream>>>(Xb, Wat, b_attn, (void*)QKV, 8192, 6144, 2048);

  // attention
  k_attn<<<dim3(16,16,4), 256, 0, stream>>>(QKV, Obf);

  // out = Obf @ W_proj + b_proj  (fp32 out)
  k_gemm<true><<<dim3(16,64), 256, 0, stream>>>(Obf, Wpt, b_proj, (void*)out, 8192, 2048, 2048);
}